// Round 5
// baseline (1802.411 us; speedup 1.0000x reference)
//
#include <hip/hip_runtime.h>
#include <math.h>

// Problem constants (fixed by reference setup_inputs)
#define B   8
#define C   64
#define HH  192
#define WWD 192
#define P   (HH*WWD)     // 36864
#define NC  2
#define NS  8
#define PP  (194*194)    // padded space map (1-px zero halo), 37636

// k_R3 tiling
#define TILE  9216       // P/4 pixels per block
#define CHUNK 1536       // 8 rows per LDS chunk

// Workspace layout (float offsets)
#define OFF_SPACE 0                    // 128 maps * PP = 4817408 (zero-padded)
#define OFF_SPART 4817408              // 128*144 per-block S partials
#define OFF_R     4835840              // 8*16*64*9 = 73728 correlations (atomic accumulated)
#define OFF_TOK2  4909568              // 8*2*64 = 1024 (atomic accumulated, needs zero)
#define OFF_U     4910592              // 8*64*2*9 = 9216 collapsed conv weights
#define OFF_STP   4919808              // 2*64*288 BN partial sums
#define OFF_SCALE 4956672              // 64
#define OFF_SHIFT 4956736              // 64
#define WS_FLOATS 4956800              // ~19.8 MB total

__device__ __forceinline__ float sigm(float x) { return 1.0f / (1.0f + expf(-x)); }

// K1: space maps (sigmoid + 1->7 ch 3x3 conv + sigmoid) into zero-padded layout,
// plus per-(map,ch) per-block partial sums (NO global atomics).
__global__ void k_space(const float* __restrict__ cs, const float* __restrict__ Wc,
                        float* __restrict__ spp, float* __restrict__ Spart) {
    int m = blockIdx.y;                       // m = b*2 + c
    int bx = blockIdx.x;
    int p = bx * 256 + threadIdx.x;           // 144*256 == P exactly
    int h = p / WWD, w = p - (p / WWD) * WWD;
    float cp[9];
    #pragma unroll
    for (int ky = 0; ky < 3; ky++)
        #pragma unroll
        for (int kx = 0; kx < 3; kx++) {
            int hh = h + ky - 1, ww = w + kx - 1;
            float v = 0.f;  // zero-pad AFTER sigmoid (conv pads class_prob with 0)
            if ((unsigned)hh < HH && (unsigned)ww < WWD)
                v = sigm(cs[m * P + hh * WWD + ww]);
            cp[ky * 3 + kx] = v;
        }
    float ch[8];
    ch[0] = cp[4];
    #pragma unroll
    for (int j = 0; j < 7; j++) {
        float a = 0.f;
        #pragma unroll
        for (int k = 0; k < 9; k++) a += Wc[j * 9 + k] * cp[k];
        ch[j + 1] = sigm(a);
    }
    #pragma unroll
    for (int q = 0; q < 8; q++)
        spp[(m * 8 + q) * PP + (h + 1) * 194 + (w + 1)] = ch[q];
    // per-wave shfl reduce -> LDS -> per-block partial (no atomics)
    __shared__ float red[4][8];
    int lane = threadIdx.x & 63, wave = threadIdx.x >> 6;
    #pragma unroll
    for (int q = 0; q < 8; q++) {
        float v = ch[q];
        for (int off = 32; off > 0; off >>= 1) v += __shfl_down(v, off);
        if (lane == 0) red[wave][q] = v;
    }
    __syncthreads();
    if (threadIdx.x < 8) {
        int q = threadIdx.x;
        Spart[(m * 8 + q) * 144 + bx] = red[0][q] + red[1][q] + red[2][q] + red[3][q];
    }
}

// K2 (restructured): 8 waves per block, one sc per wave, x chunk shared via LDS.
// Block = (pslice, scg, ig, b). x global traffic: 2x total (was 16x).
__launch_bounds__(512, 4)
__global__ void k_R3(const float* __restrict__ x, const float* __restrict__ spp,
                     float* __restrict__ R) {
    int bx = blockIdx.x;                 // pslice*2 + scg
    int pslice = bx >> 1, scg = bx & 1;
    int ig = blockIdx.y, b = blockIdx.z;
    int w = threadIdx.x >> 6, lane = threadIdx.x & 63;
    int sc = scg * 8 + w;
    int s = sc >> 1, c = sc & 1;
    const float* sp = spp + ((b * NC + c) * NS + s) * PP;
    const float* xb = x + (b * C + ig * 8) * P + pslice * TILE;

    __shared__ float xs[8 * CHUNK];      // 48 KB

    float acc[8][9];
    #pragma unroll
    for (int i = 0; i < 8; i++)
        #pragma unroll
        for (int t = 0; t < 9; t++) acc[i][t] = 0.f;

    for (int ck = 0; ck < TILE / CHUNK; ck++) {
        __syncthreads();                 // prior chunk fully consumed
        // stage: wave w loads channel w of this chunk (coalesced float4)
        {
            const float* src = xb + w * P + ck * CHUNK;
            #pragma unroll
            for (int q = 0; q < 6; q++) {
                int px = (lane + 64 * q) * 4;
                *(float4*)(&xs[w * CHUNK + px]) = *(const float4*)(src + px);
            }
        }
        __syncthreads();
        int base = pslice * TILE + ck * CHUNK;
        #pragma unroll
        for (int j = 0; j < 6; j++) {
            int pl = (lane + 64 * j) * 4;          // local pixel (4-aligned, within one row)
            int p = base + pl;
            int h = p / WWD, w0 = p - (p / WWD) * WWD;
            float g[3][6];
            #pragma unroll
            for (int ty = 0; ty < 3; ty++) {
                const float* rp = sp + (h + 2 - ty) * 194 + w0;
                #pragma unroll
                for (int cc = 0; cc < 6; cc++) g[ty][cc] = rp[cc];
            }
            #pragma unroll
            for (int i = 0; i < 8; i++) {
                float4 xv = *(const float4*)(&xs[i * CHUNK + pl]);
                #pragma unroll
                for (int ty = 0; ty < 3; ty++)
                    #pragma unroll
                    for (int tx = 0; tx < 3; tx++) {
                        float a = acc[i][ty * 3 + tx];
                        a += xv.x * g[ty][2 - tx];
                        a += xv.y * g[ty][3 - tx];
                        a += xv.z * g[ty][4 - tx];
                        a += xv.w * g[ty][5 - tx];
                        acc[i][ty * 3 + tx] = a;
                    }
            }
        }
    }

    // per-wave reduction, scattered atomic accumulate into R
    #pragma unroll
    for (int i = 0; i < 8; i++)
        #pragma unroll
        for (int t = 0; t < 9; t++) {
            float v = acc[i][t];
            for (int off = 32; off > 0; off >>= 1) v += __shfl_down(v, off);
            if (lane == 0)
                atomicAdd(&R[((b * 16 + sc) * 64 + (ig * 8 + i)) * 9 + t], v);
        }
}

// K3: tok2[b,c,d] = sum_s Wcs[s]/S[b,c,s] * sum_{i,k} Wxs[s*64+d,i,k] * R[b,s,c,i,k]
// S reduced in-block from Spart (144 partials).
__global__ void k_tok2(const float* __restrict__ Wxs, const float* __restrict__ Wcs,
                       const float* __restrict__ R, const float* __restrict__ Spart,
                       float* __restrict__ tok2) {
    int bc = blockIdx.x, s = blockIdx.y;
    int d = threadIdx.x;
    const float* spp = Spart + (bc * 8 + s) * 144;
    float sv = 0.f;
    for (int k = d; k < 144; k += 64) sv += spp[k];
    #pragma unroll
    for (int msk = 32; msk >= 1; msk >>= 1) sv += __shfl_xor(sv, msk);

    const float* Rp = R + ((bc & 1) + ((bc >> 1) * 16 + s * 2)) * 64 * 9;
    const float* Wp = Wxs + (s * C + d) * (C * 9);
    float a = 0.f;
    for (int t = 0; t < C * 9; t++) a += Wp[t] * Rp[t];
    float val = a * Wcs[s] / sv;
    atomicAdd(&tok2[bc * C + d], val);   // 8K atomics over 1024 addrs — negligible
}

// K4: collapse conv weights against tok2:  U[b][oc][m][t] = sum_ci Ws[oc,ci,t] * tok2[b,m,ci]
__global__ void k_U(const float* __restrict__ Ws, const float* __restrict__ tok2,
                    float* __restrict__ U) {
    int b = blockIdx.x, m = blockIdx.y, oc = threadIdx.x;
    const float* tp = tok2 + (b * NC + m) * C;
    float u[9];
    #pragma unroll
    for (int t = 0; t < 9; t++) u[t] = 0.f;
    for (int ci = 0; ci < C; ci++) {
        float tv = tp[ci];
        const float* wp = Ws + (oc * C + ci) * 9;
        #pragma unroll
        for (int t = 0; t < 9; t++) u[t] += wp[t] * tv;
    }
    float* up = U + ((b * C + oc) * 2 + m) * 9;
    #pragma unroll
    for (int t = 0; t < 9; t++) up[t] = u[t];
}

// Shared staging: g0/g1 34x34 halo tiles (stride 35 to break bank conflicts)
__device__ __forceinline__ void stage_g(const float* __restrict__ cs, int b, int ty0, int tx0,
                                        const float* __restrict__ Wcval,
                                        const float* __restrict__ Wattn,
                                        const float* __restrict__ Wcomb,
                                        float* h0, float* h1) {
    float wa[8], wt[8];
    #pragma unroll
    for (int s = 0; s < 8; s++) { wa[s] = Wcomb[s] * Wcval[s]; wt[s] = Wattn[s]; }
    for (int idx = threadIdx.x; idx < 34 * 34; idx += 256) {
        int i = idx / 34, j = idx - (idx / 34) * 34;
        int gy = ty0 - 1 + i, gx = tx0 - 1 + j;
        float a0 = 0.f, a1 = 0.f;
        if ((unsigned)gy < HH && (unsigned)gx < WWD) {
            int p = gy * WWD + gx;
            float c0 = sigm(cs[(b * NC + 0) * P + p]);
            float c1 = sigm(cs[(b * NC + 1) * P + p]);
            #pragma unroll
            for (int s = 0; s < 8; s++) {
                a0 += wa[s] * sigm(c0 * wt[s]);
                a1 += wa[s] * sigm(c1 * wt[s]);
            }
        }
        h0[i * 35 + j] = a0; h1[i * 35 + j] = a1;
    }
}

// K5: compute y on the fly, per-block BN partials to unique slots (NO global atomics).
__launch_bounds__(256)
__global__ void k_cs(const float* __restrict__ cs, const float* __restrict__ U,
                     const float* __restrict__ Wcval, const float* __restrict__ Wattn,
                     const float* __restrict__ Wcomb, float* __restrict__ STp) {
    int tile = blockIdx.x, ocg = blockIdx.y, b = blockIdx.z;
    int ty0 = (tile / 6) * 32, tx0 = (tile % 6) * 32;
    __shared__ float h0[34 * 35], h1[34 * 35];
    stage_g(cs, b, ty0, tx0, Wcval, Wattn, Wcomb, h0, h1);
    __syncthreads();

    int w = __builtin_amdgcn_readfirstlane(threadIdx.x >> 6);
    int lane = threadIdx.x & 63;
    int oc0 = ocg * 8 + w * 2;
    float u0[2][9], u1[2][9];
    #pragma unroll
    for (int j = 0; j < 2; j++) {
        const float* up = U + ((b * C + oc0 + j) * 2) * 9;
        #pragma unroll
        for (int t = 0; t < 9; t++) { u0[j][t] = up[t]; u1[j][t] = up[9 + t]; }
    }
    float s1[2] = {0.f, 0.f}, s2[2] = {0.f, 0.f};
    for (int it = 0; it < 4; it++) {
        int row = it * 8 + (lane >> 3);
        int c0 = (lane & 7) * 4;
        float g0v[3][6], g1v[3][6];
        #pragma unroll
        for (int dy = 0; dy < 3; dy++)
            #pragma unroll
            for (int dx = 0; dx < 6; dx++) {
                g0v[dy][dx] = h0[(row + dy) * 35 + c0 + dx];
                g1v[dy][dx] = h1[(row + dy) * 35 + c0 + dx];
            }
        #pragma unroll
        for (int j = 0; j < 2; j++)
            #pragma unroll
            for (int px = 0; px < 4; px++) {
                float y = 0.f;
                #pragma unroll
                for (int ky = 0; ky < 3; ky++)
                    #pragma unroll
                    for (int kx = 0; kx < 3; kx++) {
                        y += u0[j][ky * 3 + kx] * g0v[ky][px + kx];
                        y += u1[j][ky * 3 + kx] * g1v[ky][px + kx];
                    }
                s1[j] += y; s2[j] += y * y;
            }
    }
    #pragma unroll
    for (int j = 0; j < 2; j++) {
        float a = s1[j], q = s2[j];
        for (int off = 32; off > 0; off >>= 1) { a += __shfl_down(a, off); q += __shfl_down(q, off); }
        if (lane == 0) {
            int slot = b * 36 + tile;
            STp[(oc0 + j) * 288 + slot] = a;
            STp[64 * 288 + (oc0 + j) * 288 + slot] = q;
        }
    }
}

// K6: finalize BN scale/shift from 288 per-block partials per channel (fp64 accumulate)
__global__ void k_bnfin(const float* __restrict__ STp, const float* __restrict__ gamma,
                        const float* __restrict__ beta, float* __restrict__ scale,
                        float* __restrict__ shift) {
    int oc = threadIdx.x;
    double s = 0.0, s2 = 0.0;
    for (int k = 0; k < 288; k++) {
        s  += (double)STp[oc * 288 + k];
        s2 += (double)STp[64 * 288 + oc * 288 + k];
    }
    double n = (double)(B * P);
    double mean = s / n;
    double var = s2 / n - mean * mean;
    float sc = gamma[oc] * rsqrtf((float)var + 1e-5f);
    scale[oc] = sc;
    shift[oc] = beta[oc] - (float)mean * sc;
}

// K7: recompute y, out = x + relu(y*scale+shift)
__launch_bounds__(256)
__global__ void k_fin2(const float* __restrict__ cs, const float* __restrict__ U,
                       const float* __restrict__ Wcval, const float* __restrict__ Wattn,
                       const float* __restrict__ Wcomb, const float* __restrict__ x,
                       const float* __restrict__ scale, const float* __restrict__ shift,
                       float* __restrict__ out) {
    int tile = blockIdx.x, ocg = blockIdx.y, b = blockIdx.z;
    int ty0 = (tile / 6) * 32, tx0 = (tile % 6) * 32;
    __shared__ float h0[34 * 35], h1[34 * 35];
    stage_g(cs, b, ty0, tx0, Wcval, Wattn, Wcomb, h0, h1);
    __syncthreads();

    int w = __builtin_amdgcn_readfirstlane(threadIdx.x >> 6);
    int lane = threadIdx.x & 63;
    int oc0 = ocg * 8 + w * 2;
    float u0[2][9], u1[2][9], sc[2], sh[2];
    #pragma unroll
    for (int j = 0; j < 2; j++) {
        const float* up = U + ((b * C + oc0 + j) * 2) * 9;
        #pragma unroll
        for (int t = 0; t < 9; t++) { u0[j][t] = up[t]; u1[j][t] = up[9 + t]; }
        sc[j] = scale[oc0 + j]; sh[j] = shift[oc0 + j];
    }
    for (int it = 0; it < 4; it++) {
        int row = it * 8 + (lane >> 3);
        int c0 = (lane & 7) * 4;
        float g0v[3][6], g1v[3][6];
        #pragma unroll
        for (int dy = 0; dy < 3; dy++)
            #pragma unroll
            for (int dx = 0; dx < 6; dx++) {
                g0v[dy][dx] = h0[(row + dy) * 35 + c0 + dx];
                g1v[dy][dx] = h1[(row + dy) * 35 + c0 + dx];
            }
        #pragma unroll
        for (int j = 0; j < 2; j++) {
            float y4[4];
            #pragma unroll
            for (int px = 0; px < 4; px++) {
                float y = 0.f;
                #pragma unroll
                for (int ky = 0; ky < 3; ky++)
                    #pragma unroll
                    for (int kx = 0; kx < 3; kx++) {
                        y += u0[j][ky * 3 + kx] * g0v[ky][px + kx];
                        y += u1[j][ky * 3 + kx] * g1v[ky][px + kx];
                    }
                y4[px] = y;
            }
            int ga = (b * C + oc0 + j) * P + (ty0 + row) * WWD + tx0 + c0;
            float4 xv = *(const float4*)(x + ga);
            float4 ov;
            ov.x = fmaxf(y4[0] * sc[j] + sh[j], 0.f) + xv.x;
            ov.y = fmaxf(y4[1] * sc[j] + sh[j], 0.f) + xv.y;
            ov.z = fmaxf(y4[2] * sc[j] + sh[j], 0.f) + xv.z;
            ov.w = fmaxf(y4[3] * sc[j] + sh[j], 0.f) + xv.w;
            *(float4*)(out + ga) = ov;
        }
    }
}

extern "C" void kernel_launch(void* const* d_in, const int* in_sizes, int n_in,
                              void* d_out, int out_size, void* d_ws, size_t ws_size,
                              hipStream_t stream) {
    const float* x     = (const float*)d_in[0];
    const float* cs    = (const float*)d_in[1];
    const float* Wc    = (const float*)d_in[2];
    const float* Wxs   = (const float*)d_in[3];
    const float* Wcsp  = (const float*)d_in[4];
    const float* Wcval = (const float*)d_in[5];
    const float* Wattn = (const float*)d_in[6];
    const float* Wcomb = (const float*)d_in[7];
    const float* Wsing = (const float*)d_in[8];
    const float* gamma = (const float*)d_in[9];
    const float* beta  = (const float*)d_in[10];
    float* ws  = (float*)d_ws;
    float* out = (float*)d_out;

    float* spp   = ws + OFF_SPACE;
    float* Spart = ws + OFF_SPART;
    float* R     = ws + OFF_R;
    float* tok2  = ws + OFF_TOK2;
    float* U     = ws + OFF_U;
    float* STp   = ws + OFF_STP;
    float* scale = ws + OFF_SCALE;
    float* shift = ws + OFF_SHIFT;

    // zero padded-space halos + R + tok2 accumulators (contiguous range)
    hipMemsetAsync(ws, 0, (size_t)(OFF_TOK2 + 1024) * sizeof(float), stream);

    k_space<<<dim3(144, 16), 256, 0, stream>>>(cs, Wc, spp, Spart);
    k_R3   <<<dim3(8, 8, 8), 512, 0, stream>>>(x, spp, R);
    k_tok2 <<<dim3(16, 8), 64, 0, stream>>>(Wxs, Wcsp, R, Spart, tok2);
    k_U    <<<dim3(8, 2), 64, 0, stream>>>(Wsing, tok2, U);
    k_cs   <<<dim3(36, 8, 8), 256, 0, stream>>>(cs, U, Wcval, Wattn, Wcomb, STp);
    k_bnfin<<<1, 64, 0, stream>>>(STp, gamma, beta, scale, shift);
    k_fin2 <<<dim3(36, 8, 8), 256, 0, stream>>>(cs, U, Wcval, Wattn, Wcomb, x, scale, shift, out);
}

// Round 6
// 963.440 us; speedup vs baseline: 1.8708x; 1.8708x over previous
//
#include <hip/hip_runtime.h>
#include <math.h>

// Problem constants (fixed by reference setup_inputs)
#define B   8
#define C   64
#define HH  192
#define WWD 192
#define P   (HH*WWD)     // 36864
#define NC  2
#define NS  8
#define PP  (194*194)    // padded space map (1-px zero halo), 37636

// Workspace layout (float offsets)
#define OFF_SPACE 0                    // 128 maps * PP = 4817408 (zero-padded)
#define OFF_SPART 4817408              // 128*144 per-block S partials
#define OFF_R     4835840              // 8*16*64*9 = 73728 correlations (atomic accumulated)
#define OFF_TOK2  4909568              // 8*2*64 = 1024 (atomic accumulated, needs zero)
#define OFF_U     4910592              // 8*64*2*9 = 9216 collapsed conv weights
#define OFF_STP   4919808              // 2*64*288 BN partial sums
#define OFF_SCALE 4956672              // 64
#define OFF_SHIFT 4956736              // 64
#define WS_FLOATS 4956800              // ~19.8 MB total

__device__ __forceinline__ float sigm(float x) { return 1.0f / (1.0f + expf(-x)); }

// K1: space maps (sigmoid + 1->7 ch 3x3 conv + sigmoid) into zero-padded layout,
// plus per-(map,ch) per-block partial sums (NO global atomics).
__global__ void k_space(const float* __restrict__ cs, const float* __restrict__ Wc,
                        float* __restrict__ spp, float* __restrict__ Spart) {
    int m = blockIdx.y;                       // m = b*2 + c
    int bx = blockIdx.x;
    int p = bx * 256 + threadIdx.x;           // 144*256 == P exactly
    int h = p / WWD, w = p - (p / WWD) * WWD;
    float cp[9];
    #pragma unroll
    for (int ky = 0; ky < 3; ky++)
        #pragma unroll
        for (int kx = 0; kx < 3; kx++) {
            int hh = h + ky - 1, ww = w + kx - 1;
            float v = 0.f;  // zero-pad AFTER sigmoid (conv pads class_prob with 0)
            if ((unsigned)hh < HH && (unsigned)ww < WWD)
                v = sigm(cs[m * P + hh * WWD + ww]);
            cp[ky * 3 + kx] = v;
        }
    float ch[8];
    ch[0] = cp[4];
    #pragma unroll
    for (int j = 0; j < 7; j++) {
        float a = 0.f;
        #pragma unroll
        for (int k = 0; k < 9; k++) a += Wc[j * 9 + k] * cp[k];
        ch[j + 1] = sigm(a);
    }
    #pragma unroll
    for (int q = 0; q < 8; q++)
        spp[(m * 8 + q) * PP + (h + 1) * 194 + (w + 1)] = ch[q];
    // per-wave shfl reduce -> LDS -> per-block partial (no atomics)
    __shared__ float red[4][8];
    int lane = threadIdx.x & 63, wave = threadIdx.x >> 6;
    #pragma unroll
    for (int q = 0; q < 8; q++) {
        float v = ch[q];
        for (int off = 32; off > 0; off >>= 1) v += __shfl_down(v, off);
        if (lane == 0) red[wave][q] = v;
    }
    __syncthreads();
    if (threadIdx.x < 8) {
        int q = threadIdx.x;
        Spart[(m * 8 + q) * 144 + bx] = red[0][q] + red[1][q] + red[2][q] + red[3][q];
    }
}

// K2 (round-4 k_R2 body, proven 84 VGPR / no spill) + P split x4 for occupancy.
// Block = (sc fastest for L2 x-sharing, ig*4+pslice, b). Partials atomicAdd'ed into R.
__launch_bounds__(256, 4)
__global__ void k_R4(const float* __restrict__ x, const float* __restrict__ spp,
                     float* __restrict__ R) {
    int sc = blockIdx.x;                 // 0..15 : sc = s*2 + c  (fastest -> co-resident sharers)
    int yy = blockIdx.y;                 // ig*4 + pslice
    int ig = yy >> 2, ps = yy & 3;
    int b  = blockIdx.z;
    int s = sc >> 1, c = sc & 1;
    const float* xb = x + (b * C + ig * 8) * P;
    const float* sp = spp + ((b * NC + c) * NS + s) * PP;

    float acc[8][9];
    #pragma unroll
    for (int i = 0; i < 8; i++)
        #pragma unroll
        for (int t = 0; t < 9; t++) acc[i][t] = 0.f;

    for (int it = 0; it < 9; it++) {                 // 9 * 1024 px = P/4 per block
        int p0 = ps * (P / 4) + it * 1024 + threadIdx.x * 4;
        int h = p0 / WWD, w0 = p0 - (p0 / WWD) * WWD;
        float4 xv[8];
        #pragma unroll
        for (int i = 0; i < 8; i++) xv[i] = *(const float4*)(xb + i * P + p0);
        float g[3][6];
        #pragma unroll
        for (int ty = 0; ty < 3; ty++) {
            const float* rp = sp + (h + 2 - ty) * 194 + w0;
            #pragma unroll
            for (int cc = 0; cc < 6; cc++) g[ty][cc] = rp[cc];
        }
        #pragma unroll
        for (int ty = 0; ty < 3; ty++)
            #pragma unroll
            for (int tx = 0; tx < 3; tx++) {
                float g0 = g[ty][2 - tx], g1 = g[ty][3 - tx];
                float g2 = g[ty][4 - tx], g3 = g[ty][5 - tx];
                #pragma unroll
                for (int i = 0; i < 8; i++) {
                    float a = acc[i][ty * 3 + tx];
                    a += xv[i].x * g0; a += xv[i].y * g1;
                    a += xv[i].z * g2; a += xv[i].w * g3;
                    acc[i][ty * 3 + tx] = a;
                }
            }
    }

    __shared__ float red[4][72];
    int lane = threadIdx.x & 63, wave = threadIdx.x >> 6;
    #pragma unroll
    for (int i = 0; i < 8; i++)
        #pragma unroll
        for (int t = 0; t < 9; t++) {
            float v = acc[i][t];
            for (int off = 32; off > 0; off >>= 1) v += __shfl_down(v, off);
            if (lane == 0) red[wave][i * 9 + t] = v;
        }
    __syncthreads();
    if (threadIdx.x < 72) {
        int i = threadIdx.x / 9, t = threadIdx.x - (threadIdx.x / 9) * 9;
        float v = red[0][threadIdx.x] + red[1][threadIdx.x] +
                  red[2][threadIdx.x] + red[3][threadIdx.x];
        atomicAdd(&R[((b * 16 + sc) * 64 + (ig * 8 + i)) * 9 + t], v);  // 4 writers/addr
    }
}

// K3: tok2[b,c,d] = sum_s Wcs[s]/S[b,c,s] * sum_{i,k} Wxs[s*64+d,i,k] * R[b,s,c,i,k]
// S reduced in-block from Spart (144 partials).
__global__ void k_tok2(const float* __restrict__ Wxs, const float* __restrict__ Wcs,
                       const float* __restrict__ R, const float* __restrict__ Spart,
                       float* __restrict__ tok2) {
    int bc = blockIdx.x, s = blockIdx.y;
    int d = threadIdx.x;
    const float* spp = Spart + (bc * 8 + s) * 144;
    float sv = 0.f;
    for (int k = d; k < 144; k += 64) sv += spp[k];
    #pragma unroll
    for (int msk = 32; msk >= 1; msk >>= 1) sv += __shfl_xor(sv, msk);

    const float* Rp = R + ((bc & 1) + ((bc >> 1) * 16 + s * 2)) * 64 * 9;
    const float* Wp = Wxs + (s * C + d) * (C * 9);
    float a = 0.f;
    for (int t = 0; t < C * 9; t++) a += Wp[t] * Rp[t];
    float val = a * Wcs[s] / sv;
    atomicAdd(&tok2[bc * C + d], val);   // 8K atomics over 1024 addrs — negligible
}

// K4: collapse conv weights against tok2:  U[b][oc][m][t] = sum_ci Ws[oc,ci,t] * tok2[b,m,ci]
__global__ void k_U(const float* __restrict__ Ws, const float* __restrict__ tok2,
                    float* __restrict__ U) {
    int b = blockIdx.x, m = blockIdx.y, oc = threadIdx.x;
    const float* tp = tok2 + (b * NC + m) * C;
    float u[9];
    #pragma unroll
    for (int t = 0; t < 9; t++) u[t] = 0.f;
    for (int ci = 0; ci < C; ci++) {
        float tv = tp[ci];
        const float* wp = Ws + (oc * C + ci) * 9;
        #pragma unroll
        for (int t = 0; t < 9; t++) u[t] += wp[t] * tv;
    }
    float* up = U + ((b * C + oc) * 2 + m) * 9;
    #pragma unroll
    for (int t = 0; t < 9; t++) up[t] = u[t];
}

// Shared staging: g0/g1 34x34 halo tiles (stride 35 to break bank conflicts)
__device__ __forceinline__ void stage_g(const float* __restrict__ cs, int b, int ty0, int tx0,
                                        const float* __restrict__ Wcval,
                                        const float* __restrict__ Wattn,
                                        const float* __restrict__ Wcomb,
                                        float* h0, float* h1) {
    float wa[8], wt[8];
    #pragma unroll
    for (int s = 0; s < 8; s++) { wa[s] = Wcomb[s] * Wcval[s]; wt[s] = Wattn[s]; }
    for (int idx = threadIdx.x; idx < 34 * 34; idx += 256) {
        int i = idx / 34, j = idx - (idx / 34) * 34;
        int gy = ty0 - 1 + i, gx = tx0 - 1 + j;
        float a0 = 0.f, a1 = 0.f;
        if ((unsigned)gy < HH && (unsigned)gx < WWD) {
            int p = gy * WWD + gx;
            float c0 = sigm(cs[(b * NC + 0) * P + p]);
            float c1 = sigm(cs[(b * NC + 1) * P + p]);
            #pragma unroll
            for (int s = 0; s < 8; s++) {
                a0 += wa[s] * sigm(c0 * wt[s]);
                a1 += wa[s] * sigm(c1 * wt[s]);
            }
        }
        h0[i * 35 + j] = a0; h1[i * 35 + j] = a1;
    }
}

// K5: compute y on the fly, per-block BN partials to unique slots (NO global atomics).
__launch_bounds__(256)
__global__ void k_cs(const float* __restrict__ cs, const float* __restrict__ U,
                     const float* __restrict__ Wcval, const float* __restrict__ Wattn,
                     const float* __restrict__ Wcomb, float* __restrict__ STp) {
    int tile = blockIdx.x, ocg = blockIdx.y, b = blockIdx.z;
    int ty0 = (tile / 6) * 32, tx0 = (tile % 6) * 32;
    __shared__ float h0[34 * 35], h1[34 * 35];
    stage_g(cs, b, ty0, tx0, Wcval, Wattn, Wcomb, h0, h1);
    __syncthreads();

    int w = __builtin_amdgcn_readfirstlane(threadIdx.x >> 6);
    int lane = threadIdx.x & 63;
    int oc0 = ocg * 8 + w * 2;
    float u0[2][9], u1[2][9];
    #pragma unroll
    for (int j = 0; j < 2; j++) {
        const float* up = U + ((b * C + oc0 + j) * 2) * 9;
        #pragma unroll
        for (int t = 0; t < 9; t++) { u0[j][t] = up[t]; u1[j][t] = up[9 + t]; }
    }
    float s1[2] = {0.f, 0.f}, s2[2] = {0.f, 0.f};
    for (int it = 0; it < 4; it++) {
        int row = it * 8 + (lane >> 3);
        int c0 = (lane & 7) * 4;
        float g0v[3][6], g1v[3][6];
        #pragma unroll
        for (int dy = 0; dy < 3; dy++)
            #pragma unroll
            for (int dx = 0; dx < 6; dx++) {
                g0v[dy][dx] = h0[(row + dy) * 35 + c0 + dx];
                g1v[dy][dx] = h1[(row + dy) * 35 + c0 + dx];
            }
        #pragma unroll
        for (int j = 0; j < 2; j++)
            #pragma unroll
            for (int px = 0; px < 4; px++) {
                float y = 0.f;
                #pragma unroll
                for (int ky = 0; ky < 3; ky++)
                    #pragma unroll
                    for (int kx = 0; kx < 3; kx++) {
                        y += u0[j][ky * 3 + kx] * g0v[ky][px + kx];
                        y += u1[j][ky * 3 + kx] * g1v[ky][px + kx];
                    }
                s1[j] += y; s2[j] += y * y;
            }
    }
    #pragma unroll
    for (int j = 0; j < 2; j++) {
        float a = s1[j], q = s2[j];
        for (int off = 32; off > 0; off >>= 1) { a += __shfl_down(a, off); q += __shfl_down(q, off); }
        if (lane == 0) {
            int slot = b * 36 + tile;
            STp[(oc0 + j) * 288 + slot] = a;
            STp[64 * 288 + (oc0 + j) * 288 + slot] = q;
        }
    }
}

// K6: finalize BN scale/shift from 288 per-block partials per channel (fp64 accumulate)
__global__ void k_bnfin(const float* __restrict__ STp, const float* __restrict__ gamma,
                        const float* __restrict__ beta, float* __restrict__ scale,
                        float* __restrict__ shift) {
    int oc = threadIdx.x;
    double s = 0.0, s2 = 0.0;
    for (int k = 0; k < 288; k++) {
        s  += (double)STp[oc * 288 + k];
        s2 += (double)STp[64 * 288 + oc * 288 + k];
    }
    double n = (double)(B * P);
    double mean = s / n;
    double var = s2 / n - mean * mean;
    float sc = gamma[oc] * rsqrtf((float)var + 1e-5f);
    scale[oc] = sc;
    shift[oc] = beta[oc] - (float)mean * sc;
}

// K7: recompute y, out = x + relu(y*scale+shift)
__launch_bounds__(256)
__global__ void k_fin2(const float* __restrict__ cs, const float* __restrict__ U,
                       const float* __restrict__ Wcval, const float* __restrict__ Wattn,
                       const float* __restrict__ Wcomb, const float* __restrict__ x,
                       const float* __restrict__ scale, const float* __restrict__ shift,
                       float* __restrict__ out) {
    int tile = blockIdx.x, ocg = blockIdx.y, b = blockIdx.z;
    int ty0 = (tile / 6) * 32, tx0 = (tile % 6) * 32;
    __shared__ float h0[34 * 35], h1[34 * 35];
    stage_g(cs, b, ty0, tx0, Wcval, Wattn, Wcomb, h0, h1);
    __syncthreads();

    int w = __builtin_amdgcn_readfirstlane(threadIdx.x >> 6);
    int lane = threadIdx.x & 63;
    int oc0 = ocg * 8 + w * 2;
    float u0[2][9], u1[2][9], sc[2], sh[2];
    #pragma unroll
    for (int j = 0; j < 2; j++) {
        const float* up = U + ((b * C + oc0 + j) * 2) * 9;
        #pragma unroll
        for (int t = 0; t < 9; t++) { u0[j][t] = up[t]; u1[j][t] = up[9 + t]; }
        sc[j] = scale[oc0 + j]; sh[j] = shift[oc0 + j];
    }
    for (int it = 0; it < 4; it++) {
        int row = it * 8 + (lane >> 3);
        int c0 = (lane & 7) * 4;
        float g0v[3][6], g1v[3][6];
        #pragma unroll
        for (int dy = 0; dy < 3; dy++)
            #pragma unroll
            for (int dx = 0; dx < 6; dx++) {
                g0v[dy][dx] = h0[(row + dy) * 35 + c0 + dx];
                g1v[dy][dx] = h1[(row + dy) * 35 + c0 + dx];
            }
        #pragma unroll
        for (int j = 0; j < 2; j++) {
            float y4[4];
            #pragma unroll
            for (int px = 0; px < 4; px++) {
                float y = 0.f;
                #pragma unroll
                for (int ky = 0; ky < 3; ky++)
                    #pragma unroll
                    for (int kx = 0; kx < 3; kx++) {
                        y += u0[j][ky * 3 + kx] * g0v[ky][px + kx];
                        y += u1[j][ky * 3 + kx] * g1v[ky][px + kx];
                    }
                y4[px] = y;
            }
            int ga = (b * C + oc0 + j) * P + (ty0 + row) * WWD + tx0 + c0;
            float4 xv = *(const float4*)(x + ga);
            float4 ov;
            ov.x = fmaxf(y4[0] * sc[j] + sh[j], 0.f) + xv.x;
            ov.y = fmaxf(y4[1] * sc[j] + sh[j], 0.f) + xv.y;
            ov.z = fmaxf(y4[2] * sc[j] + sh[j], 0.f) + xv.z;
            ov.w = fmaxf(y4[3] * sc[j] + sh[j], 0.f) + xv.w;
            *(float4*)(out + ga) = ov;
        }
    }
}

extern "C" void kernel_launch(void* const* d_in, const int* in_sizes, int n_in,
                              void* d_out, int out_size, void* d_ws, size_t ws_size,
                              hipStream_t stream) {
    const float* x     = (const float*)d_in[0];
    const float* cs    = (const float*)d_in[1];
    const float* Wc    = (const float*)d_in[2];
    const float* Wxs   = (const float*)d_in[3];
    const float* Wcsp  = (const float*)d_in[4];
    const float* Wcval = (const float*)d_in[5];
    const float* Wattn = (const float*)d_in[6];
    const float* Wcomb = (const float*)d_in[7];
    const float* Wsing = (const float*)d_in[8];
    const float* gamma = (const float*)d_in[9];
    const float* beta  = (const float*)d_in[10];
    float* ws  = (float*)d_ws;
    float* out = (float*)d_out;

    float* spp   = ws + OFF_SPACE;
    float* Spart = ws + OFF_SPART;
    float* R     = ws + OFF_R;
    float* tok2  = ws + OFF_TOK2;
    float* U     = ws + OFF_U;
    float* STp   = ws + OFF_STP;
    float* scale = ws + OFF_SCALE;
    float* shift = ws + OFF_SHIFT;

    // zero padded-space halos + R + tok2 accumulators (contiguous range)
    hipMemsetAsync(ws, 0, (size_t)(OFF_TOK2 + 1024) * sizeof(float), stream);

    k_space<<<dim3(144, 16), 256, 0, stream>>>(cs, Wc, spp, Spart);
    k_R4   <<<dim3(16, 32, 8), 256, 0, stream>>>(x, spp, R);
    k_tok2 <<<dim3(16, 8), 64, 0, stream>>>(Wxs, Wcsp, R, Spart, tok2);
    k_U    <<<dim3(8, 2), 64, 0, stream>>>(Wsing, tok2, U);
    k_cs   <<<dim3(36, 8, 8), 256, 0, stream>>>(cs, U, Wcval, Wattn, Wcomb, STp);
    k_bnfin<<<1, 64, 0, stream>>>(STp, gamma, beta, scale, shift);
    k_fin2 <<<dim3(36, 8, 8), 256, 0, stream>>>(cs, U, Wcval, Wattn, Wcomb, x, scale, shift, out);
}

// Round 7
// 528.785 us; speedup vs baseline: 3.4086x; 1.8220x over previous
//
#include <hip/hip_runtime.h>
#include <math.h>

// Problem constants (fixed by reference setup_inputs)
#define B   8
#define C   64
#define HH  192
#define WWD 192
#define P   (HH*WWD)     // 36864
#define NC  2
#define NS  8
#define PP  (194*194)    // padded space map (1-px zero halo), 37636

// Workspace layout (float offsets)
#define OFF_SPACE 0                    // 128 maps * PP = 4817408 (zero-padded)
#define OFF_SPART 4817408              // 128*144 per-block S partials
#define OFF_R     4835840              // 8*16*64*9 = 73728 correlations (atomic accumulated)
#define OFF_TOK2  4909568              // 8*2*64 = 1024 (atomic accumulated, needs zero)
#define OFF_U     4910592              // 8*64*2*9 = 9216 collapsed conv weights
#define OFF_STP   4919808              // 2*64*288 BN partial sums
#define OFF_SCALE 4956672              // 64
#define OFF_SHIFT 4956736              // 64
#define WS_FLOATS 4956800              // ~19.8 MB total

__device__ __forceinline__ float sigm(float x) { return 1.0f / (1.0f + expf(-x)); }

// K1: space maps (sigmoid + 1->7 ch 3x3 conv + sigmoid) into zero-padded layout,
// plus per-(map,ch) per-block partial sums (NO global atomics).
__global__ void k_space(const float* __restrict__ cs, const float* __restrict__ Wc,
                        float* __restrict__ spp, float* __restrict__ Spart) {
    int m = blockIdx.y;                       // m = b*2 + c
    int bx = blockIdx.x;
    int p = bx * 256 + threadIdx.x;           // 144*256 == P exactly
    int h = p / WWD, w = p - (p / WWD) * WWD;
    float cp[9];
    #pragma unroll
    for (int ky = 0; ky < 3; ky++)
        #pragma unroll
        for (int kx = 0; kx < 3; kx++) {
            int hh = h + ky - 1, ww = w + kx - 1;
            float v = 0.f;  // zero-pad AFTER sigmoid (conv pads class_prob with 0)
            if ((unsigned)hh < HH && (unsigned)ww < WWD)
                v = sigm(cs[m * P + hh * WWD + ww]);
            cp[ky * 3 + kx] = v;
        }
    float ch[8];
    ch[0] = cp[4];
    #pragma unroll
    for (int j = 0; j < 7; j++) {
        float a = 0.f;
        #pragma unroll
        for (int k = 0; k < 9; k++) a += Wc[j * 9 + k] * cp[k];
        ch[j + 1] = sigm(a);
    }
    #pragma unroll
    for (int q = 0; q < 8; q++)
        spp[(m * 8 + q) * PP + (h + 1) * 194 + (w + 1)] = ch[q];
    // per-wave shfl reduce -> LDS -> per-block partial (no atomics)
    __shared__ float red[4][8];
    int lane = threadIdx.x & 63, wave = threadIdx.x >> 6;
    #pragma unroll
    for (int q = 0; q < 8; q++) {
        float v = ch[q];
        for (int off = 32; off > 0; off >>= 1) v += __shfl_down(v, off);
        if (lane == 0) red[wave][q] = v;
    }
    __syncthreads();
    if (threadIdx.x < 8) {
        int q = threadIdx.x;
        Spart[(m * 8 + q) * 144 + bx] = red[0][q] + red[1][q] + red[2][q] + red[3][q];
    }
}

// K2: round-4 k_R2 body EXACTLY (launch_bounds(256,3) -> ~84 VGPR, no spill; cap>=170 is
// required — (256,4)'s 128-VGPR cap spills this body, measured 694us vs 221us).
// P split x4 across blocks for occupancy; partials atomicAdd'ed into R (4 writers/addr).
__launch_bounds__(256, 3)
__global__ void k_R5(const float* __restrict__ x, const float* __restrict__ spp,
                     float* __restrict__ R) {
    int sc = blockIdx.x;                 // 0..15 fastest -> co-resident blocks share x slice
    int yy = blockIdx.y;                 // ig*4 + pslice
    int ig = yy >> 2, ps = yy & 3;
    int b  = blockIdx.z;
    int s = sc >> 1, c = sc & 1;
    const float* xb = x + (b * C + ig * 8) * P;
    const float* sp = spp + ((b * NC + c) * NS + s) * PP;

    float acc[8][9];
    #pragma unroll
    for (int i = 0; i < 8; i++)
        #pragma unroll
        for (int t = 0; t < 9; t++) acc[i][t] = 0.f;

    for (int it = 0; it < 9; it++) {                 // 9 * 1024 px = P/4 per block
        int p0 = ps * (P / 4) + it * 1024 + threadIdx.x * 4;
        int h = p0 / WWD, w0 = p0 - (p0 / WWD) * WWD;
        float4 xv[8];
        #pragma unroll
        for (int i = 0; i < 8; i++) xv[i] = *(const float4*)(xb + i * P + p0);
        float g[3][6];
        #pragma unroll
        for (int ty = 0; ty < 3; ty++) {
            const float* rp = sp + (h + 2 - ty) * 194 + w0;
            #pragma unroll
            for (int cc = 0; cc < 6; cc++) g[ty][cc] = rp[cc];
        }
        #pragma unroll
        for (int ty = 0; ty < 3; ty++)
            #pragma unroll
            for (int tx = 0; tx < 3; tx++) {
                float g0 = g[ty][2 - tx], g1 = g[ty][3 - tx];
                float g2 = g[ty][4 - tx], g3 = g[ty][5 - tx];
                #pragma unroll
                for (int i = 0; i < 8; i++) {
                    float a = acc[i][ty * 3 + tx];
                    a += xv[i].x * g0; a += xv[i].y * g1;
                    a += xv[i].z * g2; a += xv[i].w * g3;
                    acc[i][ty * 3 + tx] = a;
                }
            }
    }

    __shared__ float red[4][72];
    int lane = threadIdx.x & 63, wave = threadIdx.x >> 6;
    #pragma unroll
    for (int i = 0; i < 8; i++)
        #pragma unroll
        for (int t = 0; t < 9; t++) {
            float v = acc[i][t];
            for (int off = 32; off > 0; off >>= 1) v += __shfl_down(v, off);
            if (lane == 0) red[wave][i * 9 + t] = v;
        }
    __syncthreads();
    if (threadIdx.x < 72) {
        int i = threadIdx.x / 9, t = threadIdx.x - (threadIdx.x / 9) * 9;
        float v = red[0][threadIdx.x] + red[1][threadIdx.x] +
                  red[2][threadIdx.x] + red[3][threadIdx.x];
        atomicAdd(&R[((b * 16 + sc) * 64 + (ig * 8 + i)) * 9 + t], v);  // 4 writers/addr
    }
}

// K3: tok2[b,c,d] = sum_s Wcs[s]/S[b,c,s] * sum_{i,k} Wxs[s*64+d,i,k] * R[b,s,c,i,k]
// S reduced in-block from Spart (144 partials).
__global__ void k_tok2(const float* __restrict__ Wxs, const float* __restrict__ Wcs,
                       const float* __restrict__ R, const float* __restrict__ Spart,
                       float* __restrict__ tok2) {
    int bc = blockIdx.x, s = blockIdx.y;
    int d = threadIdx.x;
    const float* spp = Spart + (bc * 8 + s) * 144;
    float sv = 0.f;
    for (int k = d; k < 144; k += 64) sv += spp[k];
    #pragma unroll
    for (int msk = 32; msk >= 1; msk >>= 1) sv += __shfl_xor(sv, msk);

    const float* Rp = R + ((bc & 1) + ((bc >> 1) * 16 + s * 2)) * 64 * 9;
    const float* Wp = Wxs + (s * C + d) * (C * 9);
    float a = 0.f;
    for (int t = 0; t < C * 9; t++) a += Wp[t] * Rp[t];
    float val = a * Wcs[s] / sv;
    atomicAdd(&tok2[bc * C + d], val);   // 8K atomics over 1024 addrs — negligible
}

// K4: collapse conv weights against tok2:  U[b][oc][m][t] = sum_ci Ws[oc,ci,t] * tok2[b,m,ci]
__global__ void k_U(const float* __restrict__ Ws, const float* __restrict__ tok2,
                    float* __restrict__ U) {
    int b = blockIdx.x, m = blockIdx.y, oc = threadIdx.x;
    const float* tp = tok2 + (b * NC + m) * C;
    float u[9];
    #pragma unroll
    for (int t = 0; t < 9; t++) u[t] = 0.f;
    for (int ci = 0; ci < C; ci++) {
        float tv = tp[ci];
        const float* wp = Ws + (oc * C + ci) * 9;
        #pragma unroll
        for (int t = 0; t < 9; t++) u[t] += wp[t] * tv;
    }
    float* up = U + ((b * C + oc) * 2 + m) * 9;
    #pragma unroll
    for (int t = 0; t < 9; t++) up[t] = u[t];
}

// Shared staging: g0/g1 34x34 halo tiles (stride 35 to break bank conflicts)
__device__ __forceinline__ void stage_g(const float* __restrict__ cs, int b, int ty0, int tx0,
                                        const float* __restrict__ Wcval,
                                        const float* __restrict__ Wattn,
                                        const float* __restrict__ Wcomb,
                                        float* h0, float* h1) {
    float wa[8], wt[8];
    #pragma unroll
    for (int s = 0; s < 8; s++) { wa[s] = Wcomb[s] * Wcval[s]; wt[s] = Wattn[s]; }
    for (int idx = threadIdx.x; idx < 34 * 34; idx += 256) {
        int i = idx / 34, j = idx - (idx / 34) * 34;
        int gy = ty0 - 1 + i, gx = tx0 - 1 + j;
        float a0 = 0.f, a1 = 0.f;
        if ((unsigned)gy < HH && (unsigned)gx < WWD) {
            int p = gy * WWD + gx;
            float c0 = sigm(cs[(b * NC + 0) * P + p]);
            float c1 = sigm(cs[(b * NC + 1) * P + p]);
            #pragma unroll
            for (int s = 0; s < 8; s++) {
                a0 += wa[s] * sigm(c0 * wt[s]);
                a1 += wa[s] * sigm(c1 * wt[s]);
            }
        }
        h0[i * 35 + j] = a0; h1[i * 35 + j] = a1;
    }
}

// K5: compute y on the fly, per-block BN partials to unique slots (NO global atomics).
__launch_bounds__(256)
__global__ void k_cs(const float* __restrict__ cs, const float* __restrict__ U,
                     const float* __restrict__ Wcval, const float* __restrict__ Wattn,
                     const float* __restrict__ Wcomb, float* __restrict__ STp) {
    int tile = blockIdx.x, ocg = blockIdx.y, b = blockIdx.z;
    int ty0 = (tile / 6) * 32, tx0 = (tile % 6) * 32;
    __shared__ float h0[34 * 35], h1[34 * 35];
    stage_g(cs, b, ty0, tx0, Wcval, Wattn, Wcomb, h0, h1);
    __syncthreads();

    int w = __builtin_amdgcn_readfirstlane(threadIdx.x >> 6);
    int lane = threadIdx.x & 63;
    int oc0 = ocg * 8 + w * 2;
    float u0[2][9], u1[2][9];
    #pragma unroll
    for (int j = 0; j < 2; j++) {
        const float* up = U + ((b * C + oc0 + j) * 2) * 9;
        #pragma unroll
        for (int t = 0; t < 9; t++) { u0[j][t] = up[t]; u1[j][t] = up[9 + t]; }
    }
    float s1[2] = {0.f, 0.f}, s2[2] = {0.f, 0.f};
    for (int it = 0; it < 4; it++) {
        int row = it * 8 + (lane >> 3);
        int c0 = (lane & 7) * 4;
        float g0v[3][6], g1v[3][6];
        #pragma unroll
        for (int dy = 0; dy < 3; dy++)
            #pragma unroll
            for (int dx = 0; dx < 6; dx++) {
                g0v[dy][dx] = h0[(row + dy) * 35 + c0 + dx];
                g1v[dy][dx] = h1[(row + dy) * 35 + c0 + dx];
            }
        #pragma unroll
        for (int j = 0; j < 2; j++)
            #pragma unroll
            for (int px = 0; px < 4; px++) {
                float y = 0.f;
                #pragma unroll
                for (int ky = 0; ky < 3; ky++)
                    #pragma unroll
                    for (int kx = 0; kx < 3; kx++) {
                        y += u0[j][ky * 3 + kx] * g0v[ky][px + kx];
                        y += u1[j][ky * 3 + kx] * g1v[ky][px + kx];
                    }
                s1[j] += y; s2[j] += y * y;
            }
    }
    #pragma unroll
    for (int j = 0; j < 2; j++) {
        float a = s1[j], q = s2[j];
        for (int off = 32; off > 0; off >>= 1) { a += __shfl_down(a, off); q += __shfl_down(q, off); }
        if (lane == 0) {
            int slot = b * 36 + tile;
            STp[(oc0 + j) * 288 + slot] = a;
            STp[64 * 288 + (oc0 + j) * 288 + slot] = q;
        }
    }
}

// K6: finalize BN scale/shift from 288 per-block partials per channel (fp64 accumulate)
__global__ void k_bnfin(const float* __restrict__ STp, const float* __restrict__ gamma,
                        const float* __restrict__ beta, float* __restrict__ scale,
                        float* __restrict__ shift) {
    int oc = threadIdx.x;
    double s = 0.0, s2 = 0.0;
    for (int k = 0; k < 288; k++) {
        s  += (double)STp[oc * 288 + k];
        s2 += (double)STp[64 * 288 + oc * 288 + k];
    }
    double n = (double)(B * P);
    double mean = s / n;
    double var = s2 / n - mean * mean;
    float sc = gamma[oc] * rsqrtf((float)var + 1e-5f);
    scale[oc] = sc;
    shift[oc] = beta[oc] - (float)mean * sc;
}

// K7: recompute y, out = x + relu(y*scale+shift)
__launch_bounds__(256)
__global__ void k_fin2(const float* __restrict__ cs, const float* __restrict__ U,
                       const float* __restrict__ Wcval, const float* __restrict__ Wattn,
                       const float* __restrict__ Wcomb, const float* __restrict__ x,
                       const float* __restrict__ scale, const float* __restrict__ shift,
                       float* __restrict__ out) {
    int tile = blockIdx.x, ocg = blockIdx.y, b = blockIdx.z;
    int ty0 = (tile / 6) * 32, tx0 = (tile % 6) * 32;
    __shared__ float h0[34 * 35], h1[34 * 35];
    stage_g(cs, b, ty0, tx0, Wcval, Wattn, Wcomb, h0, h1);
    __syncthreads();

    int w = __builtin_amdgcn_readfirstlane(threadIdx.x >> 6);
    int lane = threadIdx.x & 63;
    int oc0 = ocg * 8 + w * 2;
    float u0[2][9], u1[2][9], sc[2], sh[2];
    #pragma unroll
    for (int j = 0; j < 2; j++) {
        const float* up = U + ((b * C + oc0 + j) * 2) * 9;
        #pragma unroll
        for (int t = 0; t < 9; t++) { u0[j][t] = up[t]; u1[j][t] = up[9 + t]; }
        sc[j] = scale[oc0 + j]; sh[j] = shift[oc0 + j];
    }
    for (int it = 0; it < 4; it++) {
        int row = it * 8 + (lane >> 3);
        int c0 = (lane & 7) * 4;
        float g0v[3][6], g1v[3][6];
        #pragma unroll
        for (int dy = 0; dy < 3; dy++)
            #pragma unroll
            for (int dx = 0; dx < 6; dx++) {
                g0v[dy][dx] = h0[(row + dy) * 35 + c0 + dx];
                g1v[dy][dx] = h1[(row + dy) * 35 + c0 + dx];
            }
        #pragma unroll
        for (int j = 0; j < 2; j++) {
            float y4[4];
            #pragma unroll
            for (int px = 0; px < 4; px++) {
                float y = 0.f;
                #pragma unroll
                for (int ky = 0; ky < 3; ky++)
                    #pragma unroll
                    for (int kx = 0; kx < 3; kx++) {
                        y += u0[j][ky * 3 + kx] * g0v[ky][px + kx];
                        y += u1[j][ky * 3 + kx] * g1v[ky][px + kx];
                    }
                y4[px] = y;
            }
            int ga = (b * C + oc0 + j) * P + (ty0 + row) * WWD + tx0 + c0;
            float4 xv = *(const float4*)(x + ga);
            float4 ov;
            ov.x = fmaxf(y4[0] * sc[j] + sh[j], 0.f) + xv.x;
            ov.y = fmaxf(y4[1] * sc[j] + sh[j], 0.f) + xv.y;
            ov.z = fmaxf(y4[2] * sc[j] + sh[j], 0.f) + xv.z;
            ov.w = fmaxf(y4[3] * sc[j] + sh[j], 0.f) + xv.w;
            *(float4*)(out + ga) = ov;
        }
    }
}

extern "C" void kernel_launch(void* const* d_in, const int* in_sizes, int n_in,
                              void* d_out, int out_size, void* d_ws, size_t ws_size,
                              hipStream_t stream) {
    const float* x     = (const float*)d_in[0];
    const float* cs    = (const float*)d_in[1];
    const float* Wc    = (const float*)d_in[2];
    const float* Wxs   = (const float*)d_in[3];
    const float* Wcsp  = (const float*)d_in[4];
    const float* Wcval = (const float*)d_in[5];
    const float* Wattn = (const float*)d_in[6];
    const float* Wcomb = (const float*)d_in[7];
    const float* Wsing = (const float*)d_in[8];
    const float* gamma = (const float*)d_in[9];
    const float* beta  = (const float*)d_in[10];
    float* ws  = (float*)d_ws;
    float* out = (float*)d_out;

    float* spp   = ws + OFF_SPACE;
    float* Spart = ws + OFF_SPART;
    float* R     = ws + OFF_R;
    float* tok2  = ws + OFF_TOK2;
    float* U     = ws + OFF_U;
    float* STp   = ws + OFF_STP;
    float* scale = ws + OFF_SCALE;
    float* shift = ws + OFF_SHIFT;

    // zero padded-space halos + R + tok2 accumulators (contiguous range)
    hipMemsetAsync(ws, 0, (size_t)(OFF_TOK2 + 1024) * sizeof(float), stream);

    k_space<<<dim3(144, 16), 256, 0, stream>>>(cs, Wc, spp, Spart);
    k_R5   <<<dim3(16, 32, 8), 256, 0, stream>>>(x, spp, R);
    k_tok2 <<<dim3(16, 8), 64, 0, stream>>>(Wxs, Wcsp, R, Spart, tok2);
    k_U    <<<dim3(8, 2), 64, 0, stream>>>(Wsing, tok2, U);
    k_cs   <<<dim3(36, 8, 8), 256, 0, stream>>>(cs, U, Wcval, Wattn, Wcomb, STp);
    k_bnfin<<<1, 64, 0, stream>>>(STp, gamma, beta, scale, shift);
    k_fin2 <<<dim3(36, 8, 8), 256, 0, stream>>>(cs, U, Wcval, Wattn, Wcomb, x, scale, shift, out);
}

// Round 8
// 492.815 us; speedup vs baseline: 3.6574x; 1.0730x over previous
//
#include <hip/hip_runtime.h>
#include <math.h>

// Problem constants (fixed by reference setup_inputs)
#define B   8
#define C   64
#define HH  192
#define WWD 192
#define P   (HH*WWD)     // 36864
#define NC  2
#define NS  8
#define PP  (194*194)    // padded space map (1-px zero halo), 37636

// Workspace layout (float offsets)
#define OFF_SPACE 0                    // 128 maps * PP = 4817408 (zero-padded)
#define OFF_SPART 4817408              // 128*144 per-block S partials
#define OFF_R     4835840              // 8*16*64*9 = 73728 correlations (atomic accumulated)
#define OFF_TOK2  4909568              // 8*2*64 = 1024 (atomic accumulated, needs zero)
#define OFF_U     4910592              // 8*64*2*9 = 9216 collapsed conv weights
#define OFF_STP   4919808              // 2*64*288 BN partial sums
#define OFF_SCALE 4956672              // 64
#define OFF_SHIFT 4956736              // 64
#define WS_FLOATS 4956800              // ~19.8 MB total (stay under proven ws size)

__device__ __forceinline__ float sigm(float x) { return 1.0f / (1.0f + expf(-x)); }

// K1: space maps (sigmoid + 1->7 ch 3x3 conv + sigmoid) into zero-padded layout,
// plus per-(map,ch) per-block partial sums. Blocks 144..147 write the 772 halo
// zeros per map (replaces the 19.3 MB memset).
__global__ void k_space(const float* __restrict__ cs, const float* __restrict__ Wc,
                        float* __restrict__ spp, float* __restrict__ Spart) {
    int m = blockIdx.y;                       // m = b*2 + c
    int bx = blockIdx.x;
    if (bx >= 144) {                          // halo-zero blocks
        int idx = (bx - 144) * 256 + threadIdx.x;   // 0..1023, need 772
        if (idx < 772) {
            int hy, hx;
            if (idx < 194)      { hy = 0;   hx = idx; }
            else if (idx < 388) { hy = 193; hx = idx - 194; }
            else if (idx < 580) { hy = idx - 388 + 1; hx = 0; }
            else                { hy = idx - 580 + 1; hx = 193; }
            #pragma unroll
            for (int q = 0; q < 8; q++)
                spp[(m * 8 + q) * PP + hy * 194 + hx] = 0.f;
        }
        return;
    }
    int p = bx * 256 + threadIdx.x;           // 144*256 == P exactly
    int h = p / WWD, w = p - (p / WWD) * WWD;
    float cp[9];
    #pragma unroll
    for (int ky = 0; ky < 3; ky++)
        #pragma unroll
        for (int kx = 0; kx < 3; kx++) {
            int hh = h + ky - 1, ww = w + kx - 1;
            float v = 0.f;  // zero-pad AFTER sigmoid (conv pads class_prob with 0)
            if ((unsigned)hh < HH && (unsigned)ww < WWD)
                v = sigm(cs[m * P + hh * WWD + ww]);
            cp[ky * 3 + kx] = v;
        }
    float ch[8];
    ch[0] = cp[4];
    #pragma unroll
    for (int j = 0; j < 7; j++) {
        float a = 0.f;
        #pragma unroll
        for (int k = 0; k < 9; k++) a += Wc[j * 9 + k] * cp[k];
        ch[j + 1] = sigm(a);
    }
    #pragma unroll
    for (int q = 0; q < 8; q++)
        spp[(m * 8 + q) * PP + (h + 1) * 194 + (w + 1)] = ch[q];
    __shared__ float red[4][8];
    int lane = threadIdx.x & 63, wave = threadIdx.x >> 6;
    #pragma unroll
    for (int q = 0; q < 8; q++) {
        float v = ch[q];
        for (int off = 32; off > 0; off >>= 1) v += __shfl_down(v, off);
        if (lane == 0) red[wave][q] = v;
    }
    __syncthreads();
    if (threadIdx.x < 8) {
        int q = threadIdx.x;
        Spart[(m * 8 + q) * 144 + bx] = red[0][q] + red[1][q] + red[2][q] + red[3][q];
    }
}

// K2: body identical to k_R5 (84 VGPR, no spill; launch-bounds cap must stay >=170).
// Grid flattened + XCD-aware swizzle: the 16 sc-blocks sharing one (b,ig,ps)
// x-slice land on the SAME XCD (blockIdx%8 heuristic) -> group working set
// (~0.9 MB) becomes L2-resident instead of bouncing through L3.
__launch_bounds__(256, 3)
__global__ void k_R6(const float* __restrict__ x, const float* __restrict__ spp,
                     float* __restrict__ R) {
    int flat = blockIdx.x;               // 0..4095
    int xcd = flat & 7;
    int r   = flat >> 3;                 // 0..511
    int sc  = r & 15;                    // group member: all 16 on same xcd
    int q   = r >> 4;                    // 0..31 per-XCD group slot
    int gid = q * 8 + xcd;               // 0..255 = (b, ig, ps)
    int b   = gid >> 5;
    int rem = gid & 31;
    int ig  = rem >> 2, ps = rem & 3;
    int s = sc >> 1, c = sc & 1;
    const float* xb = x + (b * C + ig * 8) * P;
    const float* sp = spp + ((b * NC + c) * NS + s) * PP;

    float acc[8][9];
    #pragma unroll
    for (int i = 0; i < 8; i++)
        #pragma unroll
        for (int t = 0; t < 9; t++) acc[i][t] = 0.f;

    for (int it = 0; it < 9; it++) {                 // 9 * 1024 px = P/4 per block
        int p0 = ps * (P / 4) + it * 1024 + threadIdx.x * 4;
        int h = p0 / WWD, w0 = p0 - (p0 / WWD) * WWD;
        float4 xv[8];
        #pragma unroll
        for (int i = 0; i < 8; i++) xv[i] = *(const float4*)(xb + i * P + p0);
        float g[3][6];
        #pragma unroll
        for (int ty = 0; ty < 3; ty++) {
            const float* rp = sp + (h + 2 - ty) * 194 + w0;
            #pragma unroll
            for (int cc = 0; cc < 6; cc++) g[ty][cc] = rp[cc];
        }
        #pragma unroll
        for (int ty = 0; ty < 3; ty++)
            #pragma unroll
            for (int tx = 0; tx < 3; tx++) {
                float g0 = g[ty][2 - tx], g1 = g[ty][3 - tx];
                float g2 = g[ty][4 - tx], g3 = g[ty][5 - tx];
                #pragma unroll
                for (int i = 0; i < 8; i++) {
                    float a = acc[i][ty * 3 + tx];
                    a += xv[i].x * g0; a += xv[i].y * g1;
                    a += xv[i].z * g2; a += xv[i].w * g3;
                    acc[i][ty * 3 + tx] = a;
                }
            }
    }

    __shared__ float red[4][72];
    int lane = threadIdx.x & 63, wave = threadIdx.x >> 6;
    #pragma unroll
    for (int i = 0; i < 8; i++)
        #pragma unroll
        for (int t = 0; t < 9; t++) {
            float v = acc[i][t];
            for (int off = 32; off > 0; off >>= 1) v += __shfl_down(v, off);
            if (lane == 0) red[wave][i * 9 + t] = v;
        }
    __syncthreads();
    if (threadIdx.x < 72) {
        int i = threadIdx.x / 9, t = threadIdx.x - (threadIdx.x / 9) * 9;
        float v = red[0][threadIdx.x] + red[1][threadIdx.x] +
                  red[2][threadIdx.x] + red[3][threadIdx.x];
        atomicAdd(&R[((b * 16 + sc) * 64 + (ig * 8 + i)) * 9 + t], v);  // 4 writers/addr
    }
}

// K3: tok2 — 4x parallelized (256 threads: wave q sums quarter of the 576-dot).
__global__ void k_tok2(const float* __restrict__ Wxs, const float* __restrict__ Wcs,
                       const float* __restrict__ R, const float* __restrict__ Spart,
                       float* __restrict__ tok2) {
    int bc = blockIdx.x, s = blockIdx.y;
    int d = threadIdx.x & 63, q = threadIdx.x >> 6;
    const float* Rp = R + ((bc & 1) + ((bc >> 1) * 16 + s * 2)) * 576;
    const float* Wp = Wxs + (s * C + d) * 576;
    float a = 0.f;
    for (int t = q * 144; t < q * 144 + 144; t++) a += Wp[t] * Rp[t];
    __shared__ float part[4][64];
    part[q][d] = a;
    __syncthreads();
    if (q == 0) {
        const float* sp = Spart + (bc * 8 + s) * 144;
        float sv = 0.f;
        for (int k = d; k < 144; k += 64) sv += sp[k];
        #pragma unroll
        for (int msk = 32; msk >= 1; msk >>= 1) sv += __shfl_xor(sv, msk);
        float at = part[0][d] + part[1][d] + part[2][d] + part[3][d];
        atomicAdd(&tok2[bc * C + d], at * Wcs[s] / sv);
    }
}

// K4: U — 4x parallelized (wave q handles 16 of 64 ci).
__global__ void k_U(const float* __restrict__ Ws, const float* __restrict__ tok2,
                    float* __restrict__ U) {
    int b = blockIdx.x, m = blockIdx.y;
    int oc = threadIdx.x & 63, q = threadIdx.x >> 6;
    const float* tp = tok2 + (b * NC + m) * C;
    float u[9];
    #pragma unroll
    for (int t = 0; t < 9; t++) u[t] = 0.f;
    for (int ci = q * 16; ci < q * 16 + 16; ci++) {
        float tv = tp[ci];
        const float* wp = Ws + (oc * C + ci) * 9;
        #pragma unroll
        for (int t = 0; t < 9; t++) u[t] += wp[t] * tv;
    }
    __shared__ float up[4][64][9];
    #pragma unroll
    for (int t = 0; t < 9; t++) up[q][oc][t] = u[t];
    __syncthreads();
    if (q == 0) {
        float* uo = U + ((b * C + oc) * 2 + m) * 9;
        #pragma unroll
        for (int t = 0; t < 9; t++)
            uo[t] = up[0][oc][t] + up[1][oc][t] + up[2][oc][t] + up[3][oc][t];
    }
}

// Shared staging: g0/g1 34x34 halo tiles (stride 35 to break bank conflicts)
__device__ __forceinline__ void stage_g(const float* __restrict__ cs, int b, int ty0, int tx0,
                                        const float* __restrict__ Wcval,
                                        const float* __restrict__ Wattn,
                                        const float* __restrict__ Wcomb,
                                        float* h0, float* h1) {
    float wa[8], wt[8];
    #pragma unroll
    for (int s = 0; s < 8; s++) { wa[s] = Wcomb[s] * Wcval[s]; wt[s] = Wattn[s]; }
    for (int idx = threadIdx.x; idx < 34 * 34; idx += 256) {
        int i = idx / 34, j = idx - (idx / 34) * 34;
        int gy = ty0 - 1 + i, gx = tx0 - 1 + j;
        float a0 = 0.f, a1 = 0.f;
        if ((unsigned)gy < HH && (unsigned)gx < WWD) {
            int p = gy * WWD + gx;
            float c0 = sigm(cs[(b * NC + 0) * P + p]);
            float c1 = sigm(cs[(b * NC + 1) * P + p]);
            #pragma unroll
            for (int s = 0; s < 8; s++) {
                a0 += wa[s] * sigm(c0 * wt[s]);
                a1 += wa[s] * sigm(c1 * wt[s]);
            }
        }
        h0[i * 35 + j] = a0; h1[i * 35 + j] = a1;
    }
}

// K5: compute y on the fly, per-block BN partials to unique slots.
__launch_bounds__(256)
__global__ void k_cs(const float* __restrict__ cs, const float* __restrict__ U,
                     const float* __restrict__ Wcval, const float* __restrict__ Wattn,
                     const float* __restrict__ Wcomb, float* __restrict__ STp) {
    int tile = blockIdx.x, ocg = blockIdx.y, b = blockIdx.z;
    int ty0 = (tile / 6) * 32, tx0 = (tile % 6) * 32;
    __shared__ float h0[34 * 35], h1[34 * 35];
    stage_g(cs, b, ty0, tx0, Wcval, Wattn, Wcomb, h0, h1);
    __syncthreads();

    int w = __builtin_amdgcn_readfirstlane(threadIdx.x >> 6);
    int lane = threadIdx.x & 63;
    int oc0 = ocg * 8 + w * 2;
    float u0[2][9], u1[2][9];
    #pragma unroll
    for (int j = 0; j < 2; j++) {
        const float* up = U + ((b * C + oc0 + j) * 2) * 9;
        #pragma unroll
        for (int t = 0; t < 9; t++) { u0[j][t] = up[t]; u1[j][t] = up[9 + t]; }
    }
    float s1[2] = {0.f, 0.f}, s2[2] = {0.f, 0.f};
    for (int it = 0; it < 4; it++) {
        int row = it * 8 + (lane >> 3);
        int c0 = (lane & 7) * 4;
        float g0v[3][6], g1v[3][6];
        #pragma unroll
        for (int dy = 0; dy < 3; dy++)
            #pragma unroll
            for (int dx = 0; dx < 6; dx++) {
                g0v[dy][dx] = h0[(row + dy) * 35 + c0 + dx];
                g1v[dy][dx] = h1[(row + dy) * 35 + c0 + dx];
            }
        #pragma unroll
        for (int j = 0; j < 2; j++)
            #pragma unroll
            for (int px = 0; px < 4; px++) {
                float y = 0.f;
                #pragma unroll
                for (int ky = 0; ky < 3; ky++)
                    #pragma unroll
                    for (int kx = 0; kx < 3; kx++) {
                        y += u0[j][ky * 3 + kx] * g0v[ky][px + kx];
                        y += u1[j][ky * 3 + kx] * g1v[ky][px + kx];
                    }
                s1[j] += y; s2[j] += y * y;
            }
    }
    #pragma unroll
    for (int j = 0; j < 2; j++) {
        float a = s1[j], qq = s2[j];
        for (int off = 32; off > 0; off >>= 1) { a += __shfl_down(a, off); qq += __shfl_down(qq, off); }
        if (lane == 0) {
            int slot = b * 36 + tile;
            STp[(oc0 + j) * 288 + slot] = a;
            STp[64 * 288 + (oc0 + j) * 288 + slot] = qq;
        }
    }
}

// K6: finalize BN — 4x parallelized partial-sum of 288 slots per channel.
__global__ void k_bnfin(const float* __restrict__ STp, const float* __restrict__ gamma,
                        const float* __restrict__ beta, float* __restrict__ scale,
                        float* __restrict__ shift) {
    int oc = threadIdx.x & 63, q = threadIdx.x >> 6;
    double s = 0.0, s2 = 0.0;
    for (int k = q * 72; k < q * 72 + 72; k++) {
        s  += (double)STp[oc * 288 + k];
        s2 += (double)STp[64 * 288 + oc * 288 + k];
    }
    __shared__ double rs[4][64], rs2[4][64];
    rs[q][oc] = s; rs2[q][oc] = s2;
    __syncthreads();
    if (q == 0) {
        double st = rs[0][oc] + rs[1][oc] + rs[2][oc] + rs[3][oc];
        double st2 = rs2[0][oc] + rs2[1][oc] + rs2[2][oc] + rs2[3][oc];
        double n = (double)(B * P);
        double mean = st / n;
        double var = st2 / n - mean * mean;
        float sc = gamma[oc] * rsqrtf((float)var + 1e-5f);
        scale[oc] = sc;
        shift[oc] = beta[oc] - (float)mean * sc;
    }
}

// K7: recompute y, out = x + relu(y*scale+shift)
__launch_bounds__(256)
__global__ void k_fin2(const float* __restrict__ cs, const float* __restrict__ U,
                       const float* __restrict__ Wcval, const float* __restrict__ Wattn,
                       const float* __restrict__ Wcomb, const float* __restrict__ x,
                       const float* __restrict__ scale, const float* __restrict__ shift,
                       float* __restrict__ out) {
    int tile = blockIdx.x, ocg = blockIdx.y, b = blockIdx.z;
    int ty0 = (tile / 6) * 32, tx0 = (tile % 6) * 32;
    __shared__ float h0[34 * 35], h1[34 * 35];
    stage_g(cs, b, ty0, tx0, Wcval, Wattn, Wcomb, h0, h1);
    __syncthreads();

    int w = __builtin_amdgcn_readfirstlane(threadIdx.x >> 6);
    int lane = threadIdx.x & 63;
    int oc0 = ocg * 8 + w * 2;
    float u0[2][9], u1[2][9], sc[2], sh[2];
    #pragma unroll
    for (int j = 0; j < 2; j++) {
        const float* up = U + ((b * C + oc0 + j) * 2) * 9;
        #pragma unroll
        for (int t = 0; t < 9; t++) { u0[j][t] = up[t]; u1[j][t] = up[9 + t]; }
        sc[j] = scale[oc0 + j]; sh[j] = shift[oc0 + j];
    }
    for (int it = 0; it < 4; it++) {
        int row = it * 8 + (lane >> 3);
        int c0 = (lane & 7) * 4;
        float g0v[3][6], g1v[3][6];
        #pragma unroll
        for (int dy = 0; dy < 3; dy++)
            #pragma unroll
            for (int dx = 0; dx < 6; dx++) {
                g0v[dy][dx] = h0[(row + dy) * 35 + c0 + dx];
                g1v[dy][dx] = h1[(row + dy) * 35 + c0 + dx];
            }
        #pragma unroll
        for (int j = 0; j < 2; j++) {
            float y4[4];
            #pragma unroll
            for (int px = 0; px < 4; px++) {
                float y = 0.f;
                #pragma unroll
                for (int ky = 0; ky < 3; ky++)
                    #pragma unroll
                    for (int kx = 0; kx < 3; kx++) {
                        y += u0[j][ky * 3 + kx] * g0v[ky][px + kx];
                        y += u1[j][ky * 3 + kx] * g1v[ky][px + kx];
                    }
                y4[px] = y;
            }
            int ga = (b * C + oc0 + j) * P + (ty0 + row) * WWD + tx0 + c0;
            float4 xv = *(const float4*)(x + ga);
            float4 ov;
            ov.x = fmaxf(y4[0] * sc[j] + sh[j], 0.f) + xv.x;
            ov.y = fmaxf(y4[1] * sc[j] + sh[j], 0.f) + xv.y;
            ov.z = fmaxf(y4[2] * sc[j] + sh[j], 0.f) + xv.z;
            ov.w = fmaxf(y4[3] * sc[j] + sh[j], 0.f) + xv.w;
            *(float4*)(out + ga) = ov;
        }
    }
}

extern "C" void kernel_launch(void* const* d_in, const int* in_sizes, int n_in,
                              void* d_out, int out_size, void* d_ws, size_t ws_size,
                              hipStream_t stream) {
    const float* x     = (const float*)d_in[0];
    const float* cs    = (const float*)d_in[1];
    const float* Wc    = (const float*)d_in[2];
    const float* Wxs   = (const float*)d_in[3];
    const float* Wcsp  = (const float*)d_in[4];
    const float* Wcval = (const float*)d_in[5];
    const float* Wattn = (const float*)d_in[6];
    const float* Wcomb = (const float*)d_in[7];
    const float* Wsing = (const float*)d_in[8];
    const float* gamma = (const float*)d_in[9];
    const float* beta  = (const float*)d_in[10];
    float* ws  = (float*)d_ws;
    float* out = (float*)d_out;

    float* spp   = ws + OFF_SPACE;
    float* Spart = ws + OFF_SPART;
    float* R     = ws + OFF_R;
    float* tok2  = ws + OFF_TOK2;
    float* U     = ws + OFF_U;
    float* STp   = ws + OFF_STP;
    float* scale = ws + OFF_SCALE;
    float* shift = ws + OFF_SHIFT;

    // zero only R + tok2 accumulators (contiguous, 0.3 MB); halos zeroed by k_space
    hipMemsetAsync(R, 0, (size_t)(73728 + 1024) * sizeof(float), stream);

    k_space<<<dim3(148, 16), 256, 0, stream>>>(cs, Wc, spp, Spart);
    k_R6   <<<4096, 256, 0, stream>>>(x, spp, R);
    k_tok2 <<<dim3(16, 8), 256, 0, stream>>>(Wxs, Wcsp, R, Spart, tok2);
    k_U    <<<dim3(8, 2), 256, 0, stream>>>(Wsing, tok2, U);
    k_cs   <<<dim3(36, 8, 8), 256, 0, stream>>>(cs, U, Wcval, Wattn, Wcomb, STp);
    k_bnfin<<<1, 256, 0, stream>>>(STp, gamma, beta, scale, shift);
    k_fin2 <<<dim3(36, 8, 8), 256, 0, stream>>>(cs, U, Wcval, Wattn, Wcomb, x, scale, shift, out);
}